// Round 15
// baseline (98.981 us; speedup 1.0000x reference)
//
#include <hip/hip_runtime.h>
#include <hip/hip_bf16.h>
#include <stdint.h>

// Round 14: VISIBILITY PROBE. Identical structure to round 13, but each block
// processes TWO patches (pb, then pb^512) so the dispatch runs ~2x and crosses
// the 43.6us fill threshold into rocprof's top-5 -> first real counters since
// round 4. Each patch is computed twice chip-wide (by two different blocks)
// with bit-identical math -> benign identical duplicate ws stores. Rep 1 is
// HBM-cold, rep 2 is L3-warm: dur vs 2x-single decomposes the cold-stage cost.

#define P2 256
#define CF 32
#define ROWP 40   // bf16 row pitch: 80 B

using bf16x8 = __attribute__((ext_vector_type(8))) short;
using f32x4  = __attribute__((ext_vector_type(4))) float;

__device__ __forceinline__ short bfs(float x) {
    __hip_bfloat16 h = __float2bfloat16(x);
    union { __hip_bfloat16 h; short s; } u; u.h = h; return u.s;
}

__global__ __launch_bounds__(256, 4)
void ncut_mfma_kernel(const float* __restrict__ pred,
                      const float* __restrict__ feat,
                      float* __restrict__ ws)
{
    __shared__ short  fb[P2][ROWP];
    __shared__ float2 sp[P2];
    __shared__ float  red[8];

    const int t  = threadIdx.x;
    const int l  = t & 63;
    const int w  = t >> 6;
    const int b  = blockIdx.x;
    const int pb0 = ((b & 7) << 7) | (b >> 3);   // XCD-affinity swizzle

    for (int rep = 0; rep < 2; ++rep) {
        const int pb = pb0 ^ (rep << 9);         // rep1: flip batch-half bit
        const int n  = pb >> 8, pl = pb & 255;
        const int hp = pl >> 4, wp = pl & 15;

        const int pq  = t >> 2;
        const int y   = pq >> 2;
        const int k4  = pq & 3;
        const int cg0 = t & 3;

        if (rep) __syncthreads();    // protect LDS reuse across reps

        const float p_mine = pred[(((size_t)n * 256) + hp * 16 + y) * 256
                                  + wp * 16 + k4 * 4 + cg0];
        const float* qbase = feat + (((size_t)n * CF) * 256 + hp * 16 + y) * 256
                                  + wp * 16 + k4 * 4;
        float4 v[8];
#pragma unroll
        for (int it = 0; it < 2; ++it) {
            const int cg = cg0 + it * 4;
#pragma unroll
            for (int cc = 0; cc < 4; ++cc)
                v[it * 4 + cc] = *(const float4*)(qbase + (size_t)(cg * 4 + cc) * 65536);
        }

        float psq0 = 0.f, psq1 = 0.f, psq2 = 0.f, psq3 = 0.f;
#pragma unroll
        for (int q8 = 0; q8 < 8; ++q8) {
            psq0 = fmaf(v[q8].x, v[q8].x, psq0);
            psq1 = fmaf(v[q8].y, v[q8].y, psq1);
            psq2 = fmaf(v[q8].z, v[q8].z, psq2);
            psq3 = fmaf(v[q8].w, v[q8].w, psq3);
        }
        psq0 += __shfl_xor(psq0, 1); psq0 += __shfl_xor(psq0, 2);
        psq1 += __shfl_xor(psq1, 1); psq1 += __shfl_xor(psq1, 2);
        psq2 += __shfl_xor(psq2, 1); psq2 += __shfl_xor(psq2, 2);
        psq3 += __shfl_xor(psq3, 1); psq3 += __shfl_xor(psq3, 2);
        float mysq = (cg0 == 0) ? psq0 : (cg0 == 1) ? psq1 : (cg0 == 2) ? psq2 : psq3;
        sp[pq * 4 + cg0] = make_float2(mysq, p_mine);

#pragma unroll
        for (int it = 0; it < 2; ++it) {
            const int cg = cg0 + it * 4;
            short4 o0 = { bfs(v[it*4+0].x), bfs(v[it*4+1].x), bfs(v[it*4+2].x), bfs(v[it*4+3].x) };
            short4 o1 = { bfs(v[it*4+0].y), bfs(v[it*4+1].y), bfs(v[it*4+2].y), bfs(v[it*4+3].y) };
            short4 o2 = { bfs(v[it*4+0].z), bfs(v[it*4+1].z), bfs(v[it*4+2].z), bfs(v[it*4+3].z) };
            short4 o3 = { bfs(v[it*4+0].w), bfs(v[it*4+1].w), bfs(v[it*4+2].w), bfs(v[it*4+3].w) };
            *(short4*)&fb[pq * 4 + 0][cg * 4] = o0;
            *(short4*)&fb[pq * 4 + 1][cg * 4] = o1;
            *(short4*)&fb[pq * 4 + 2][cg * 4] = o2;
            *(short4*)&fb[pq * 4 + 3][cg * 4] = o3;
        }
        __syncthreads();

        const int lr = l & 15;
        const int lk = l >> 4;

        bf16x8 af[4];
#pragma unroll
        for (int r = 0; r < 4; ++r)
            af[r] = *(const bf16x8*)&fb[(w * 4 + r) * 16 + lr][lk * 8];

        const float L50  = 72.134752f;
        const float L100 = 144.269504f;
        const float CSPL = -4.3333804e-8f;

        float a[4][4];
        float api[4][4];
#pragma unroll
        for (int tii = 0; tii < 4; ++tii)
#pragma unroll
            for (int r = 0; r < 4; ++r) {
                const int qi = lk * 4 + r;
                const float dq = (float)(qi - lr);
                a[tii][r] = fmaf(dq * dq, CSPL, -L50 * sp[(w * 4 + tii) * 16 + qi].x);
                api[tii][r] = 0.f;
            }

        const f32x4 zero = {0.f, 0.f, 0.f, 0.f};
        const float tif = (float)(w * 4);

#pragma unroll 2
        for (int tj = 0; tj < 16; ++tj) {
            const bf16x8 bfj = *(const bf16x8*)&fb[tj * 16 + lr][lk * 8];
            const float2 spc = sp[tj * 16 + lr];
            const float bbase = -L50 * spc.x;
            const float tjf = (float)tj;

            f32x4 acc[4];
#pragma unroll
            for (int tii = 0; tii < 4; ++tii)
                acc[tii] = __builtin_amdgcn_mfma_f32_16x16x32_bf16(af[tii], bfj, zero, 0, 0, 0);

#pragma unroll
            for (int tii = 0; tii < 4; ++tii) {
                const float dyf = tif + (float)tii - tjf;
                const float bj = fmaf(dyf * dyf, CSPL, bbase);
                const bool diag = (w * 4 + tii) == tj;

                float E0 = fmaf(L100, acc[tii][0], a[tii][0] + bj);
                float E1 = fmaf(L100, acc[tii][1], a[tii][1] + bj);
                float E2 = fmaf(L100, acc[tii][2], a[tii][2] + bj);
                float E3 = fmaf(L100, acc[tii][3], a[tii][3] + bj);
                const float mxi = fmaxf(fmaxf(E0, E1), fmaxf(E2, E3));

                if (diag || __any(mxi > -126.f)) {
                    if (diag) {
                        if ((lk * 4 + 0) == lr) E0 = 0.f;
                        if ((lk * 4 + 1) == lr) E1 = 0.f;
                        if ((lk * 4 + 2) == lr) E2 = 0.f;
                        if ((lk * 4 + 3) == lr) E3 = 0.f;
                    }
                    api[tii][0] = fmaf(__builtin_amdgcn_exp2f(E0), spc.y, api[tii][0]);
                    api[tii][1] = fmaf(__builtin_amdgcn_exp2f(E1), spc.y, api[tii][1]);
                    api[tii][2] = fmaf(__builtin_amdgcn_exp2f(E2), spc.y, api[tii][2]);
                    api[tii][3] = fmaf(__builtin_amdgcn_exp2f(E3), spc.y, api[tii][3]);
                }
            }
        }

        float assoc = 0.f, cut = 0.f;
#pragma unroll
        for (int tii = 0; tii < 4; ++tii)
#pragma unroll
            for (int r = 0; r < 4; ++r) {
                const float pi = sp[(w * 4 + tii) * 16 + lk * 4 + r].y;
                assoc += api[tii][r];
                cut   = fmaf(1.f - pi, api[tii][r], cut);
            }
#pragma unroll
        for (int off = 32; off; off >>= 1) {
            assoc += __shfl_down(assoc, off);
            cut   += __shfl_down(cut,  off);
        }
        if (l == 0) { red[2 * w] = assoc; red[2 * w + 1] = cut; }
        __syncthreads();
        if (t == 0) {
            float aa = red[0] + red[2] + red[4] + red[6];
            float cc = red[1] + red[3] + red[5] + red[7];
            ws[pb] = cc / (aa + 1e-5f);   // identical value from both writers
        }
    }
}

__global__ __launch_bounds__(256)
void ncut_reduce_kernel(const float* __restrict__ ws, float* __restrict__ out)
{
    __shared__ float red[4];
    const int t = threadIdx.x;
    float s = ws[t] + ws[t + 256] + ws[t + 512] + ws[t + 768];
#pragma unroll
    for (int off = 32; off; off >>= 1)
        s += __shfl_down(s, off);
    if ((t & 63) == 0) red[t >> 6] = s;
    __syncthreads();
    if (t == 0)
        out[0] = (red[0] + red[1] + red[2] + red[3]) * (1.0f / 1024.0f);
}

extern "C" void kernel_launch(void* const* d_in, const int* in_sizes, int n_in,
                              void* d_out, int out_size, void* d_ws, size_t ws_size,
                              hipStream_t stream)
{
    const float* pred = (const float*)d_in[0];   // (4,1,256,256) f32
    const float* feat = (const float*)d_in[1];   // (4,32,256,256) f32
    float* out = (float*)d_out;                  // scalar f32
    float* ws  = (float*)d_ws;                   // per-patch losses (1024 f32)

    ncut_mfma_kernel<<<1024, 256, 0, stream>>>(pred, feat, ws);
    ncut_reduce_kernel<<<1, 256, 0, stream>>>(ws, out);
}